// Round 5
// baseline (917.683 us; speedup 1.0000x reference)
//
#include <hip/hip_runtime.h>
#include <hip/hip_bf16.h>
#include <stdint.h>

typedef __bf16 bf16_t;
typedef __bf16 bf16x8 __attribute__((ext_vector_type(8)));
typedef __bf16 bf16x4 __attribute__((ext_vector_type(4)));
typedef float f32x4 __attribute__((ext_vector_type(4)));

#define BATCH 8192
#define INDIM 2048
#define UNITS 2048
#define NG3   6144   // 3*UNITS
#define KCAT  4096   // INDIM + UNITS
#define NCAT  4096   // 2*UNITS (r,u gates)

// ---------------------------------------------------------------- prep: A
// Acat[b][0:2048] = bf16(x[b]), Acat[b][2048:4096] = bf16(h[b])
__global__ __launch_bounds__(256) void build_acat(
    const float* __restrict__ x, const float* __restrict__ h,
    bf16_t* __restrict__ acat) {
  int64_t i4 = (int64_t)blockIdx.x * 256 + threadIdx.x;  // one float4 each
  int row = (int)(i4 >> 10);           // 1024 float4 per 4096-col row
  int c4  = (int)(i4 & 1023) * 4;
  const float* src = (c4 < INDIM) ? (x + (int64_t)row * INDIM + c4)
                                  : (h + (int64_t)row * UNITS + (c4 - INDIM));
  f32x4 v = *reinterpret_cast<const f32x4*>(src);
  bf16_t o[4] = {(bf16_t)v.x, (bf16_t)v.y, (bf16_t)v.z, (bf16_t)v.w};
  *reinterpret_cast<uint64_t*>(acat + i4 * 4) = *reinterpret_cast<const uint64_t*>(o);
}

// ---------------------------------------------------------------- prep: W^T
// W is 2048 x 6144 (row-major). For output col n:
//   n < 4096  -> WcatT[n][cat_koff + k]  (ld KCAT)   [r,u gates]
//   n >= 4096 -> WsT[n-4096][k]          (ld INDIM)  [h gate]
__global__ __launch_bounds__(256) void transpose_w(
    const float* __restrict__ W, bf16_t* __restrict__ WcatT, int cat_koff,
    bf16_t* __restrict__ WsT) {
  __shared__ float tile[32][33];
  int k0 = blockIdx.x * 32;
  int n0 = blockIdx.y * 32;
  int tx = threadIdx.x & 31;
  int ty = threadIdx.x >> 5;  // 0..7
#pragma unroll
  for (int i = 0; i < 4; ++i)
    tile[ty + i * 8][tx] = W[(int64_t)(k0 + ty + i * 8) * NG3 + n0 + tx];
  __syncthreads();
#pragma unroll
  for (int i = 0; i < 4; ++i) {
    int n = n0 + ty + i * 8;
    int k = k0 + tx;
    bf16_t v = (bf16_t)tile[tx][ty + i * 8];
    if (n < NCAT) WcatT[(int64_t)n * KCAT + cat_koff + k] = v;
    else          WsT[(int64_t)(n - NCAT) * INDIM + k] = v;
  }
}

// ---------------------------------------------------------------- GEMM
// C[M][N] (CT, ld ldc) = A[M][K] (bf16, ld lda) * BT[N][K]^T (bf16, ld K)
// m97 structure: 128x128 tile, BK=64, 256 thr / 4 waves (2x2, 64x64 each),
// global_load_lds width-16 staging, mfma_f32_16x16x32_bf16.
__device__ inline void gload_lds16(const void* g, void* l) {
  __builtin_amdgcn_global_load_lds(
      (const __attribute__((address_space(1))) void*)g,
      (__attribute__((address_space(3))) void*)l, 16, 0, 0);
}

template <typename CT>
__global__ __launch_bounds__(256) void gemm_bt(
    const bf16_t* __restrict__ A, int lda,
    const bf16_t* __restrict__ BT,           // ld == K
    CT* __restrict__ C, int ldc, int K) {
  __shared__ bf16_t smA[128 * 64];
  __shared__ bf16_t smB[128 * 64];
  const int tid  = threadIdx.x;
  const int lane = tid & 63;
  const int wave = tid >> 6;
  const int bm = blockIdx.y * 128;
  const int bn = blockIdx.x * 128;
  const int wm = (wave >> 1) * 64;
  const int wn = (wave & 1) * 64;

  f32x4 acc[4][4];
  const f32x4 zero = {0.f, 0.f, 0.f, 0.f};
#pragma unroll
  for (int i = 0; i < 4; ++i)
#pragma unroll
    for (int j = 0; j < 4; ++j) acc[i][j] = zero;

  // staging geometry: 16 chunks of 1 KiB (8 rows x 64 cols bf16); chunk = wave*4+it
  const int arow = lane >> 3;          // row within chunk
  const int acol = (lane & 7) * 8;     // col (bf16 elems)
  // fragment geometry
  const int frow = lane & 15;
  const int fk   = (lane >> 4) * 8;

  for (int k0 = 0; k0 < K; k0 += 64) {
#pragma unroll
    for (int it = 0; it < 4; ++it) {
      int c = wave * 4 + it;
      const bf16_t* ga = A  + (int64_t)(bm + c * 8 + arow) * lda + k0 + acol;
      gload_lds16(ga, &smA[c * 512]);
      const bf16_t* gb = BT + (int64_t)(bn + c * 8 + arow) * K   + k0 + acol;
      gload_lds16(gb, &smB[c * 512]);
    }
    __syncthreads();   // drains vmcnt (compiler inserts waitcnt before barrier)
#pragma unroll
    for (int ks = 0; ks < 64; ks += 32) {
      bf16x8 af[4], bf[4];
#pragma unroll
      for (int mi = 0; mi < 4; ++mi)
        af[mi] = *reinterpret_cast<const bf16x8*>(
            &smA[(wm + mi * 16 + frow) * 64 + ks + fk]);
#pragma unroll
      for (int ni = 0; ni < 4; ++ni)
        bf[ni] = *reinterpret_cast<const bf16x8*>(
            &smB[(wn + ni * 16 + frow) * 64 + ks + fk]);
#pragma unroll
      for (int mi = 0; mi < 4; ++mi)
#pragma unroll
        for (int ni = 0; ni < 4; ++ni)
          acc[mi][ni] = __builtin_amdgcn_mfma_f32_16x16x32_bf16(
              af[mi], bf[ni], acc[mi][ni], 0, 0, 0);
    }
    __syncthreads();
  }

  // C/D layout: col = lane&15, row = (lane>>4)*4 + reg   [m89/m91 verified]
  const int crow0 = bm + wm + (lane >> 4) * 4;
  const int ccol0 = bn + wn + (lane & 15);
#pragma unroll
  for (int mi = 0; mi < 4; ++mi)
#pragma unroll
    for (int ni = 0; ni < 4; ++ni)
#pragma unroll
      for (int i = 0; i < 4; ++i)
        C[(int64_t)(crow0 + mi * 16 + i) * ldc + ccol0 + ni * 16] =
            (CT)acc[mi][ni][i];
}

// ---------------------------------------------------------------- gate1
// RH = bf16( sigmoid(S_r + br) * h )    [reset-after GRU: (r .* h) @ Wh_h]
__global__ __launch_bounds__(256) void gate1(
    const bf16_t* __restrict__ S, const float* __restrict__ h_tm1,
    const float* __restrict__ bias, bf16_t* __restrict__ RH) {
  int64_t i4 = (int64_t)blockIdx.x * 256 + threadIdx.x;  // group of 4 elems
  int row = (int)(i4 >> 9);            // 512 groups per 2048-col row
  int col = (int)(i4 & 511) * 4;
  bf16x4 sr4 = *reinterpret_cast<const bf16x4*>(&S[(int64_t)row * NCAT + col]);
  f32x4 hv = *reinterpret_cast<const f32x4*>(&h_tm1[(int64_t)row * UNITS + col]);
  f32x4 br = *reinterpret_cast<const f32x4*>(&bias[col]);
  bf16_t o[4];
#pragma unroll
  for (int j = 0; j < 4; ++j) {
    float r = 1.f / (1.f + __expf(-((float)sr4[j] + br[j])));
    o[j] = (bf16_t)(r * hv[j]);
  }
  *reinterpret_cast<uint64_t*>(&RH[(int64_t)row * UNITS + col]) =
      *reinterpret_cast<const uint64_t*>(o);
}

// ---------------------------------------------------------------- epilogue
// u = sig(S_u + bu); cand = tanh(XH + HH2 + bh); out = u*h + (1-u)*cand
// XH is f32 ALIASED with out (same element index -> safe); HH2 bf16.
__global__ __launch_bounds__(256) void epilogue(
    const bf16_t* __restrict__ S, const float* __restrict__ XH,
    const bf16_t* __restrict__ HH2, const float* __restrict__ h_tm1,
    const float* __restrict__ bias, float* __restrict__ out) {
  int64_t i4 = (int64_t)blockIdx.x * 256 + threadIdx.x;  // group of 4 elems
  int row = (int)(i4 >> 9);            // 512 groups per 2048-col row
  int col = (int)(i4 & 511) * 4;
  bf16x4 su4 = *reinterpret_cast<const bf16x4*>(&S[(int64_t)row * NCAT + UNITS + col]);
  f32x4 xh = *reinterpret_cast<const f32x4*>(&XH[(int64_t)row * UNITS + col]);
  bf16x4 hh4 = *reinterpret_cast<const bf16x4*>(&HH2[(int64_t)row * UNITS + col]);
  f32x4 hv = *reinterpret_cast<const f32x4*>(&h_tm1[(int64_t)row * UNITS + col]);
  f32x4 bu = *reinterpret_cast<const f32x4*>(&bias[UNITS + col]);
  f32x4 bh = *reinterpret_cast<const f32x4*>(&bias[2 * UNITS + col]);
  f32x4 o;
#pragma unroll
  for (int j = 0; j < 4; ++j) {
    float u = 1.f / (1.f + __expf(-((float)su4[j] + bu[j])));
    float z = xh[j] + (float)hh4[j] + bh[j];
    float e2 = __expf(2.f * z);
    float cand = (e2 - 1.f) / (e2 + 1.f);   // tanh(z)
    o[j] = u * hv[j] + (1.f - u) * cand;
  }
  *reinterpret_cast<f32x4*>(&out[(int64_t)row * UNITS + col]) = o;
}

// ---------------------------------------------------------------- launch
extern "C" void kernel_launch(void* const* d_in, const int* in_sizes, int n_in,
                              void* d_out, int out_size, void* d_ws, size_t ws_size,
                              hipStream_t stream) {
  const float* x    = (const float*)d_in[0];
  const float* h    = (const float*)d_in[1];
  const float* Wi   = (const float*)d_in[2];
  const float* Wh   = (const float*)d_in[3];
  const float* bias = (const float*)d_in[4];
  float* out = (float*)d_out;

  char* ws = (char*)d_ws;
  // workspace layout — peak 176 MB (round-3 verified safe):
  //   [0,64M)    Acat  bf16 8192x4096   -> first 32MB reused as HH2 after GEMM2
  //   [64M,96M)  WcatT bf16 4096x4096ru -> reused as RH bf16 after GEMM1
  //   [96M,104M) W2T   bf16 2048x2048 (Wi h-gate)
  //   [104M,112M)W3T   bf16 2048x2048 (Wh h-gate)
  //   [112M,176M)S     bf16 8192x4096 (r | u pre-activations)
  // XH (f32 8192x2048) lives in d_out, elementwise-aliased by the epilogue.
  bf16_t* Acat  = (bf16_t*)(ws);
  bf16_t* WcatT = (bf16_t*)(ws + (64LL << 20));
  bf16_t* W2T   = (bf16_t*)(ws + (96LL << 20));
  bf16_t* W3T   = (bf16_t*)(ws + (104LL << 20));
  bf16_t* Sb    = (bf16_t*)(ws + (112LL << 20));
  bf16_t* RH    = WcatT;            // reuse after GEMM1 (stream order)
  bf16_t* HH2   = Acat;             // reuse after GEMM1+GEMM2 (stream order)
  float*  XH    = out;              // f32 scratch aliased with output

  build_acat<<<32768, 256, 0, stream>>>(x, h, Acat);
  dim3 tg(64, 192);  // (2048/32 k-tiles, 6144/32 n-tiles)
  transpose_w<<<tg, 256, 0, stream>>>(Wi, WcatT, 0,    W2T);
  transpose_w<<<tg, 256, 0, stream>>>(Wh, WcatT, 2048, W3T);

  // S = [x|h] @ [Wi_ru; Wh_ru]   (M=8192, N=4096, K=4096) -> bf16
  gemm_bt<bf16_t><<<dim3(NCAT / 128, BATCH / 128), 256, 0, stream>>>(
      Acat, KCAT, WcatT, Sb, NCAT, KCAT);
  // XH = x @ Wi_h   (K=2048) -> f32 into d_out
  gemm_bt<float><<<dim3(UNITS / 128, BATCH / 128), 256, 0, stream>>>(
      Acat, KCAT, W2T, XH, UNITS, INDIM);
  // RH = bf16(sigmoid(S_r + br) * h)   (overwrites WcatT)
  gate1<<<16384, 256, 0, stream>>>(Sb, h, bias, RH);
  // HH2 = (r.*h) @ Wh_h   (K=2048) -> bf16 (overwrites Acat, dead now)
  gemm_bt<bf16_t><<<dim3(UNITS / 128, BATCH / 128), 256, 0, stream>>>(
      RH, UNITS, W3T, HH2, UNITS, UNITS);

  epilogue<<<16384, 256, 0, stream>>>(Sb, XH, HH2, h, bias, out);
}